// Round 1
// baseline (260.040 us; speedup 1.0000x reference)
//
#include <hip/hip_runtime.h>
#include <hip/hip_bf16.h>

#define NB 8
#define NC 128
#define NN 2048
#define NH 4
#define HD 32
#define NOUT 128

typedef _Float16 half8 __attribute__((ext_vector_type(8)));
typedef float f32x4 __attribute__((ext_vector_type(4)));

__device__ __forceinline__ f32x4 mfma16(half8 a, half8 b, f32x4 c) {
  return __builtin_amdgcn_mfma_f32_16x16x32_f16(a, b, c, 0, 0, 0);
}

// ---------------- Kernel 1: QKV projections ----------------
// grid: 256 blocks (b = bid&7, n0 = (bid>>3)*64), 256 threads, wave = head.
// q,k stored [b][h][n][32] fp16; v stored transposed [b][h][32][n] fp16.
__global__ __launch_bounds__(256) void k_proj(
    const float* __restrict__ x, const float* __restrict__ Wq,
    const float* __restrict__ Wk, const float* __restrict__ Wv,
    _Float16* __restrict__ qo, _Float16* __restrict__ ko, _Float16* __restrict__ vto)
{
  const int bid = blockIdx.x;
  const int b  = bid & 7;
  const int n0 = (bid >> 3) * 64;
  const int h  = threadIdx.x >> 6;
  const int l  = threadIdx.x & 63;
  const int lr = l & 15, lg = l >> 4;

  // A-fragments of x_t (row n = lr, k c = lg*8+j) — reused for Q,K (as A) and V (as B)
  half8 a[4][4];
#pragma unroll
  for (int rf = 0; rf < 4; ++rf)
#pragma unroll
    for (int kc = 0; kc < 4; ++kc)
#pragma unroll
      for (int j = 0; j < 8; ++j)
        a[rf][kc][j] = (_Float16)x[(size_t)(b*NC + kc*32 + lg*8 + j)*NN + n0 + rf*16 + lr];

#pragma unroll
  for (int m = 0; m < 2; ++m) {
    const float* W = m ? Wk : Wq;
    _Float16* dst  = m ? ko : qo;
    f32x4 acc[4][2] = {};
#pragma unroll
    for (int kc = 0; kc < 4; ++kc) {
      half8 wb[2];
#pragma unroll
      for (int cf = 0; cf < 2; ++cf)
#pragma unroll
        for (int j = 0; j < 8; ++j)
          wb[cf][j] = (_Float16)W[(size_t)(h*NC + kc*32 + lg*8 + j)*HD + cf*16 + lr];
#pragma unroll
      for (int rf = 0; rf < 4; ++rf)
#pragma unroll
        for (int cf = 0; cf < 2; ++cf)
          acc[rf][cf] = mfma16(a[rf][kc], wb[cf], acc[rf][cf]);
    }
#pragma unroll
    for (int rf = 0; rf < 4; ++rf)
#pragma unroll
      for (int cf = 0; cf < 2; ++cf)
#pragma unroll
        for (int r = 0; r < 4; ++r)
          dst[((size_t)(b*NH + h)*NN + n0 + rf*16 + lg*4 + r)*HD + cf*16 + lr] =
              (_Float16)acc[rf][cf][r];
  }

  // vT = Wv^T · x  (rows d, cols n) -> coalesced [d][n] store
  {
    half8 aw[2][4];
#pragma unroll
    for (int rf = 0; rf < 2; ++rf)
#pragma unroll
      for (int kc = 0; kc < 4; ++kc)
#pragma unroll
        for (int j = 0; j < 8; ++j)
          aw[rf][kc][j] = (_Float16)Wv[(size_t)(h*NC + kc*32 + lg*8 + j)*HD + rf*16 + lr];
    f32x4 acc[2][4] = {};
#pragma unroll
    for (int kc = 0; kc < 4; ++kc)
#pragma unroll
      for (int rf = 0; rf < 2; ++rf)
#pragma unroll
        for (int nf = 0; nf < 4; ++nf)
          acc[rf][nf] = mfma16(aw[rf][kc], a[nf][kc], acc[rf][nf]);
#pragma unroll
    for (int rf = 0; rf < 2; ++rf)
#pragma unroll
      for (int nf = 0; nf < 4; ++nf)
#pragma unroll
        for (int r = 0; r < 4; ++r)
          vto[((size_t)(b*NH + h)*HD + rf*16 + lg*4 + r)*NN + n0 + nf*16 + lr] =
              (_Float16)acc[rf][nf][r];
  }
}

// ---------------- Kernel 2: attention + adj + W_o ----------------
union SMem {
  _Float16 p[NH * 32 * 72];                       // per-head p tiles, row stride 72 (pad)
  struct { _Float16 ocat[32 * 136]; float ot[128 * 36]; } ep;  // epilogue buffers
};

__global__ __launch_bounds__(256) void k_attn(
    const _Float16* __restrict__ q, const _Float16* __restrict__ k,
    const _Float16* __restrict__ vt, const float* __restrict__ Wo,
    float* __restrict__ outT, float* __restrict__ adj)
{
  __shared__ SMem sm;
  const int bid = blockIdx.x;
  const int b  = bid & 7;              // XCD-swizzle: one batch per XCD -> K/V L2-resident
  const int n0 = (bid >> 3) * 32;
  const int h  = threadIdx.x >> 6;
  const int l  = threadIdx.x & 63;
  const int lr = l & 15, lg = l >> 4;

  const _Float16* qh = q  + (size_t)(b*NH + h) * NN * HD;
  const _Float16* kh = k  + (size_t)(b*NH + h) * NN * HD;
  const _Float16* vh = vt + (size_t)(b*NH + h) * HD * NN;

  half8 qa[2];
  qa[0] = *(const half8*)(qh + (size_t)(n0 + lr)*HD + lg*8);
  qa[1] = *(const half8*)(qh + (size_t)(n0 + 16 + lr)*HD + lg*8);

  const float c1 = 0.25504527f;   // (1/sqrt(32)) * log2(e)
  const float c2 = 17.3123405f;   // 12 * log2(e)  (fixed shift; exact after normalize)

  // ---- Pass 1: row sums of exp2(s*c1 - c2) ----
  float rs[2][4] = {};
  for (int mt = 0; mt < NN/16; ++mt) {
    half8 kb = *(const half8*)(kh + (size_t)(mt*16 + lr)*HD + lg*8);
    f32x4 z{};
    f32x4 s0 = mfma16(qa[0], kb, z);
    f32x4 s1 = mfma16(qa[1], kb, z);
#pragma unroll
    for (int r = 0; r < 4; ++r) {
      rs[0][r] += __builtin_amdgcn_exp2f(s0[r]*c1 - c2);
      rs[1][r] += __builtin_amdgcn_exp2f(s1[r]*c1 - c2);
    }
  }
#pragma unroll
  for (int rf = 0; rf < 2; ++rf)
#pragma unroll
    for (int r = 0; r < 4; ++r) {
      float v = rs[rf][r];
      v += __shfl_xor(v, 1); v += __shfl_xor(v, 2);
      v += __shfl_xor(v, 4); v += __shfl_xor(v, 8);
      rs[rf][r] = 1.0f / v;     // now holds 1/rowsum, uniform across the 16-lane group
    }

  // ---- Pass 2: p tiles -> LDS; PV MFMA; adj (head-mean) write ----
  f32x4 oacc[2][2] = {};
  const int tr = threadIdx.x >> 3;
  const int tc = (threadIdx.x & 7) * 8;

  for (int mt2 = 0; mt2 < NN/64; ++mt2) {
#pragma unroll
    for (int st = 0; st < 4; ++st) {
      half8 kb = *(const half8*)(kh + (size_t)(mt2*64 + st*16 + lr)*HD + lg*8);
      f32x4 z{};
      f32x4 s0 = mfma16(qa[0], kb, z);
      f32x4 s1 = mfma16(qa[1], kb, z);
#pragma unroll
      for (int r = 0; r < 4; ++r) {
        sm.p[h*2304 + (lg*4 + r)*72 + st*16 + lr] =
            (_Float16)(__builtin_amdgcn_exp2f(s0[r]*c1 - c2) * rs[0][r]);
        sm.p[h*2304 + (16 + lg*4 + r)*72 + st*16 + lr] =
            (_Float16)(__builtin_amdgcn_exp2f(s1[r]*c1 - c2) * rs[1][r]);
      }
    }
    __syncthreads();
    // PV: A = p (via LDS transpose), B = vT (global, 16B contiguous k-dim)
#pragma unroll
    for (int kc = 0; kc < 2; ++kc) {
      half8 pa0 = *(const half8*)(&sm.p[h*2304 + lr*72 + kc*32 + lg*8]);
      half8 pa1 = *(const half8*)(&sm.p[h*2304 + (16 + lr)*72 + kc*32 + lg*8]);
      half8 vb0 = *(const half8*)(vh + (size_t)lr*NN        + mt2*64 + kc*32 + lg*8);
      half8 vb1 = *(const half8*)(vh + (size_t)(16 + lr)*NN + mt2*64 + kc*32 + lg*8);
      oacc[0][0] = mfma16(pa0, vb0, oacc[0][0]);
      oacc[0][1] = mfma16(pa0, vb1, oacc[0][1]);
      oacc[1][0] = mfma16(pa1, vb0, oacc[1][0]);
      oacc[1][1] = mfma16(pa1, vb1, oacc[1][1]);
    }
    // adj tile: mean over the 4 heads, coalesced fp32 write
    {
      float a8[8] = {};
#pragma unroll
      for (int h2 = 0; h2 < 4; ++h2) {
        half8 pv = *(const half8*)(&sm.p[h2*2304 + tr*72 + tc]);
#pragma unroll
        for (int i = 0; i < 8; ++i) a8[i] += (float)pv[i];
      }
      size_t base = ((size_t)(b*NN) + n0 + tr)*NN + mt2*64 + tc;
      f32x4 w0 = {a8[0]*0.25f, a8[1]*0.25f, a8[2]*0.25f, a8[3]*0.25f};
      f32x4 w1 = {a8[4]*0.25f, a8[5]*0.25f, a8[6]*0.25f, a8[7]*0.25f};
      *(f32x4*)(adj + base)     = w0;
      *(f32x4*)(adj + base + 4) = w1;
    }
    __syncthreads();
  }

  // ---- Epilogue: concat heads -> W_o -> transposed coalesced store ----
#pragma unroll
  for (int rf = 0; rf < 2; ++rf)
#pragma unroll
    for (int df = 0; df < 2; ++df)
#pragma unroll
      for (int r = 0; r < 4; ++r)
        sm.ep.ocat[(rf*16 + lg*4 + r)*136 + h*32 + df*16 + lr] = (_Float16)oacc[rf][df][r];
  __syncthreads();

  f32x4 o2[2][2] = {};
#pragma unroll
  for (int kc = 0; kc < 4; ++kc) {
    half8 a2[2];
    a2[0] = *(const half8*)(&sm.ep.ocat[lr*136        + kc*32 + lg*8]);
    a2[1] = *(const half8*)(&sm.ep.ocat[(16 + lr)*136 + kc*32 + lg*8]);
    half8 wb[2];
#pragma unroll
    for (int of = 0; of < 2; ++of)
#pragma unroll
      for (int j = 0; j < 8; ++j)
        wb[of][j] = (_Float16)Wo[(size_t)(kc*32 + lg*8 + j)*NOUT + h*32 + of*16 + lr];
#pragma unroll
    for (int rf = 0; rf < 2; ++rf)
#pragma unroll
      for (int of = 0; of < 2; ++of)
        o2[rf][of] = mfma16(a2[rf], wb[of], o2[rf][of]);
  }
  // ot region is disjoint from ocat; p no longer in use -> no barrier needed here
#pragma unroll
  for (int rf = 0; rf < 2; ++rf)
#pragma unroll
    for (int of = 0; of < 2; ++of)
#pragma unroll
      for (int r = 0; r < 4; ++r)
        sm.ep.ot[(h*32 + of*16 + lr)*36 + rf*16 + lg*4 + r] = o2[rf][of][r];
  __syncthreads();
  {
    int o  = threadIdx.x >> 1;
    int nn = (threadIdx.x & 1) * 16;
    float* dst = outT + ((size_t)(b*NOUT) + o)*NN + n0 + nn;
#pragma unroll
    for (int i = 0; i < 4; ++i)
      *(f32x4*)(dst + i*4) = *(const f32x4*)(&sm.ep.ot[o*36 + nn + i*4]);
  }
}

extern "C" void kernel_launch(void* const* d_in, const int* in_sizes, int n_in,
                              void* d_out, int out_size, void* d_ws, size_t ws_size,
                              hipStream_t stream) {
  const float* x  = (const float*)d_in[0];
  const float* Wq = (const float*)d_in[1];
  const float* Wk = (const float*)d_in[2];
  const float* Wv = (const float*)d_in[3];
  const float* Wo = (const float*)d_in[4];

  float* outT = (float*)d_out;                       // [B,128,N]
  float* adj  = outT + (size_t)NB * NOUT * NN;       // [B,N,N]

  const size_t qkv_elems = (size_t)NB * NH * NN * HD;  // 2,097,152 fp16 each
  _Float16* qw = (_Float16*)d_ws;
  _Float16* kw = qw + qkv_elems;
  _Float16* vw = kw + qkv_elems;

  k_proj<<<dim3(NB * (NN/64)), dim3(256), 0, stream>>>(x, Wq, Wk, Wv, qw, kw, vw);
  k_attn<<<dim3(NB * (NN/32)), dim3(256), 0, stream>>>(qw, kw, vw, Wo, outT, adj);
}